// Round 1
// baseline (182.121 us; speedup 1.0000x reference)
//
#include <hip/hip_runtime.h>

// CausalSelfAttention: B=4, T=2048, D=1024, DA=256, fp32 in/out.
// Pipeline: convert->bf16, QKV GEMMs (MFMA), scores+exp GEMM, row-normalize,
// PV GEMM. attn_weights materialized in d_out (required output).

typedef short bf16x8 __attribute__((ext_vector_type(8)));   // 8 bf16 in 4 VGPRs
typedef float f32x4  __attribute__((ext_vector_type(4)));
typedef unsigned int  u32x4 __attribute__((ext_vector_type(4)));
typedef unsigned short u16x4 __attribute__((ext_vector_type(4)));

static __device__ __forceinline__ unsigned short f2bf(float f) {
    union { float f; unsigned int u; } v; v.f = f;
    unsigned int u = v.u;
    return (unsigned short)((u + 0x7FFFu + ((u >> 16) & 1u)) >> 16);  // RNE
}

// ---------------- conversion kernels ----------------

__global__ void convert_bf16(const float* __restrict__ in,
                             unsigned short* __restrict__ out, int n4) {
    int i = blockIdx.x * blockDim.x + threadIdx.x;
    if (i >= n4) return;
    f32x4 v = ((const f32x4*)in)[i];
    u16x4 o;
    o[0] = f2bf(v[0]); o[1] = f2bf(v[1]); o[2] = f2bf(v[2]); o[3] = f2bf(v[3]);
    ((u16x4*)out)[i] = o;
}

// W[K][N] (fp32) -> Wt[N][K] (bf16), scaled.
__global__ void tconvert(const float* __restrict__ W,
                         unsigned short* __restrict__ Wt,
                         int K, int N, float scale) {
    __shared__ float tile[32][33];
    int n0 = blockIdx.x * 32, k0 = blockIdx.y * 32;
    int tx = threadIdx.x, ty = threadIdx.y;
#pragma unroll
    for (int r = 0; r < 4; ++r)
        tile[ty + 8 * r][tx] = W[(size_t)(k0 + ty + 8 * r) * N + n0 + tx];
    __syncthreads();
#pragma unroll
    for (int r = 0; r < 4; ++r)
        Wt[(size_t)(n0 + ty + 8 * r) * K + k0 + tx] = f2bf(tile[tx][ty + 8 * r] * scale);
}

// ---------------- GEMM (A[M,K] @ Bt[N,K]^T), bf16 in, bf16 out ----------------

#define BM 128
#define BN 128
#define BK 64
#define BKP 72   // padded LDS leading dim (+16B) to break bank conflicts

__global__ __launch_bounds__(256) void gemm_bt_bf16(
    const unsigned short* __restrict__ A, int lda,
    const unsigned short* __restrict__ Bt, int ldb,
    unsigned short* __restrict__ C, int ldc, int K)
{
    __shared__ __align__(16) unsigned short As[BM][BKP];
    __shared__ __align__(16) unsigned short Bs[BN][BKP];
    int tid = threadIdx.x;
    int m0 = blockIdx.y * BM, n0 = blockIdx.x * BN;
    int lane = tid & 63, wave = tid >> 6;
    int wr = (wave >> 1) * 64, wc = (wave & 1) * 64;
    int fr = lane & 15, fk = (lane >> 4) * 8;
    int srow = tid >> 3, scol = (tid & 7) * 8;
    f32x4 acc[4][4] = {};

    for (int kt = 0; kt < K; kt += BK) {
        const unsigned short* Ap = A + (size_t)(m0 + srow) * lda + kt + scol;
        const unsigned short* Bp = Bt + (size_t)(n0 + srow) * ldb + kt + scol;
#pragma unroll
        for (int i = 0; i < 4; ++i) {
            *(u32x4*)(&As[srow + 32 * i][scol]) = *(const u32x4*)(Ap + (size_t)32 * i * lda);
            *(u32x4*)(&Bs[srow + 32 * i][scol]) = *(const u32x4*)(Bp + (size_t)32 * i * ldb);
        }
        __syncthreads();
#pragma unroll
        for (int ks = 0; ks < BK; ks += 32) {
            bf16x8 af[4], bfr[4];
#pragma unroll
            for (int i = 0; i < 4; ++i) af[i]  = *(const bf16x8*)(&As[wr + 16 * i + fr][ks + fk]);
#pragma unroll
            for (int j = 0; j < 4; ++j) bfr[j] = *(const bf16x8*)(&Bs[wc + 16 * j + fr][ks + fk]);
#pragma unroll
            for (int i = 0; i < 4; ++i)
#pragma unroll
                for (int j = 0; j < 4; ++j)
                    acc[i][j] = __builtin_amdgcn_mfma_f32_16x16x32_bf16(af[i], bfr[j], acc[i][j], 0, 0, 0);
        }
        __syncthreads();
    }
#pragma unroll
    for (int i = 0; i < 4; ++i)
#pragma unroll
        for (int j = 0; j < 4; ++j)
#pragma unroll
            for (int r = 0; r < 4; ++r) {
                int row = m0 + wr + 16 * i + (lane >> 4) * 4 + r;
                int col = n0 + wc + 16 * j + fr;
                C[(size_t)row * ldc + col] = f2bf(acc[i][j][r]);
            }
}

// ---------------- scores: E = exp(Q Kt^T), causal-masked, fp32 out ----------------
// QK buffer: [8192][512] bf16, Q = cols 0:256, K = cols 256:512. Per batch z.

__global__ __launch_bounds__(256) void gemm_scores(
    const unsigned short* __restrict__ QK, float* __restrict__ Wout)
{
    int b = blockIdx.z;
    int m0 = blockIdx.y * BM, n0 = blockIdx.x * BN;
    if (n0 > m0) return;  // tile fully above diagonal
    const unsigned short* A  = QK + (size_t)b * 2048 * 512;
    const unsigned short* Bt = A + 256;
    float* Wb = Wout + (size_t)b * 2048 * 2048;

    __shared__ __align__(16) unsigned short As[BM][BKP];
    __shared__ __align__(16) unsigned short Bs[BN][BKP];
    int tid = threadIdx.x;
    int lane = tid & 63, wave = tid >> 6;
    int wr = (wave >> 1) * 64, wc = (wave & 1) * 64;
    int fr = lane & 15, fk = (lane >> 4) * 8;
    int srow = tid >> 3, scol = (tid & 7) * 8;
    f32x4 acc[4][4] = {};

    for (int kt = 0; kt < 256; kt += BK) {
        const unsigned short* Ap = A  + (size_t)(m0 + srow) * 512 + kt + scol;
        const unsigned short* Bp = Bt + (size_t)(n0 + srow) * 512 + kt + scol;
#pragma unroll
        for (int i = 0; i < 4; ++i) {
            *(u32x4*)(&As[srow + 32 * i][scol]) = *(const u32x4*)(Ap + (size_t)32 * i * 512);
            *(u32x4*)(&Bs[srow + 32 * i][scol]) = *(const u32x4*)(Bp + (size_t)32 * i * 512);
        }
        __syncthreads();
#pragma unroll
        for (int ks = 0; ks < BK; ks += 32) {
            bf16x8 af[4], bfr[4];
#pragma unroll
            for (int i = 0; i < 4; ++i) af[i]  = *(const bf16x8*)(&As[wr + 16 * i + fr][ks + fk]);
#pragma unroll
            for (int j = 0; j < 4; ++j) bfr[j] = *(const bf16x8*)(&Bs[wc + 16 * j + fr][ks + fk]);
#pragma unroll
            for (int i = 0; i < 4; ++i)
#pragma unroll
                for (int j = 0; j < 4; ++j)
                    acc[i][j] = __builtin_amdgcn_mfma_f32_16x16x32_bf16(af[i], bfr[j], acc[i][j], 0, 0, 0);
        }
        __syncthreads();
    }
#pragma unroll
    for (int i = 0; i < 4; ++i)
#pragma unroll
        for (int j = 0; j < 4; ++j)
#pragma unroll
            for (int r = 0; r < 4; ++r) {
                int q = m0 + wr + 16 * i + (lane >> 4) * 4 + r;
                int k = n0 + wc + 16 * j + fr;
                Wb[(size_t)q * 2048 + k] = (k <= q) ? expf(acc[i][j][r]) : 0.f;
            }
}

// ---------------- row-sum + normalize (in place on weights) ----------------

__global__ __launch_bounds__(256) void softmax_norm(float* __restrict__ Wt) {
    int r = blockIdx.x;          // 0..8191 == b*2048+q
    int q = r & 2047;
    float* row = Wt + (size_t)r * 2048;
    int tid = threadIdx.x;
    f32x4 v0 = *((const f32x4*)row + 2 * tid);
    f32x4 v1 = *((const f32x4*)row + 2 * tid + 1);
    int c0 = tid * 8;
    float vals[8];
    float s = 0.f;
#pragma unroll
    for (int j = 0; j < 8; ++j) {
        float e = (j < 4) ? v0[j] : v1[j - 4];
        e = (c0 + j <= q) ? e : 0.f;
        vals[j] = e; s += e;
    }
#pragma unroll
    for (int off = 32; off > 0; off >>= 1) s += __shfl_xor(s, off, 64);
    __shared__ float red[4];
    if ((tid & 63) == 0) red[tid >> 6] = s;
    __syncthreads();
    float inv = 1.0f / (red[0] + red[1] + red[2] + red[3]);
#pragma unroll
    for (int j = 0; j < 4; ++j) { v0[j] = vals[j] * inv; v1[j] = vals[4 + j] * inv; }
    *((f32x4*)row + 2 * tid) = v0;
    *((f32x4*)row + 2 * tid + 1) = v1;
}

// ---------------- PV: O = P(fp32,normalized) @ V, causal k-limit ----------------

__global__ __launch_bounds__(256) void gemm_pv(
    const float* __restrict__ P, const unsigned short* __restrict__ Vt,
    float* __restrict__ O)
{
    int b = blockIdx.z;
    int m0 = blockIdx.y * BM, n0 = blockIdx.x * BN;
    const float* Pb = P + (size_t)b * 2048 * 2048;
    const unsigned short* Bt = Vt + (size_t)b * 2048;   // ldb = 8192
    float* Ob = O + (size_t)b * 2048 * 1024;
    int Klim = (blockIdx.y + 1) * BM;

    __shared__ __align__(16) unsigned short As[BM][BKP];
    __shared__ __align__(16) unsigned short Bs[BN][BKP];
    int tid = threadIdx.x;
    int lane = tid & 63, wave = tid >> 6;
    int wr = (wave >> 1) * 64, wc = (wave & 1) * 64;
    int fr = lane & 15, fk = (lane >> 4) * 8;
    int srow = tid >> 3, scol = (tid & 7) * 8;
    f32x4 acc[4][4] = {};

    for (int kt = 0; kt < Klim; kt += BK) {
        const float* Ap = Pb + (size_t)(m0 + srow) * 2048 + kt + scol;
        const unsigned short* Bp = Bt + (size_t)(n0 + srow) * 8192 + kt + scol;
#pragma unroll
        for (int i = 0; i < 4; ++i) {
            f32x4 a0 = *(const f32x4*)(Ap + (size_t)32 * i * 2048);
            f32x4 a1 = *(const f32x4*)(Ap + (size_t)32 * i * 2048 + 4);
            unsigned short t[8];
#pragma unroll
            for (int j = 0; j < 4; ++j) { t[j] = f2bf(a0[j]); t[4 + j] = f2bf(a1[j]); }
            *(u32x4*)(&As[srow + 32 * i][scol]) = *(const u32x4*)t;
            *(u32x4*)(&Bs[srow + 32 * i][scol]) = *(const u32x4*)(Bp + (size_t)32 * i * 8192);
        }
        __syncthreads();
#pragma unroll
        for (int ks = 0; ks < BK; ks += 32) {
            bf16x8 af[4], bfr[4];
#pragma unroll
            for (int i = 0; i < 4; ++i) af[i]  = *(const bf16x8*)(&As[wr + 16 * i + fr][ks + fk]);
#pragma unroll
            for (int j = 0; j < 4; ++j) bfr[j] = *(const bf16x8*)(&Bs[wc + 16 * j + fr][ks + fk]);
#pragma unroll
            for (int i = 0; i < 4; ++i)
#pragma unroll
                for (int j = 0; j < 4; ++j)
                    acc[i][j] = __builtin_amdgcn_mfma_f32_16x16x32_bf16(af[i], bfr[j], acc[i][j], 0, 0, 0);
        }
        __syncthreads();
    }
#pragma unroll
    for (int i = 0; i < 4; ++i)
#pragma unroll
        for (int j = 0; j < 4; ++j)
#pragma unroll
            for (int r = 0; r < 4; ++r) {
                int row = m0 + wr + 16 * i + (lane >> 4) * 4 + r;
                int col = n0 + wc + 16 * j + fr;
                Ob[(size_t)row * 1024 + col] = acc[i][j][r];
            }
}

// ---------------- launcher ----------------

extern "C" void kernel_launch(void* const* d_in, const int* in_sizes, int n_in,
                              void* d_out, int out_size, void* d_ws, size_t ws_size,
                              hipStream_t stream) {
    (void)in_sizes; (void)n_in; (void)out_size; (void)ws_size;
    const float* x  = (const float*)d_in[0];
    const float* Wq = (const float*)d_in[1];
    const float* Wk = (const float*)d_in[2];
    const float* Wv = (const float*)d_in[3];
    const int B = 4, T = 2048, D = 1024, DA = 256;
    const int M = B * T;  // 8192

    char* ws = (char*)d_ws;
    size_t off = 0;
    auto alloc = [&](size_t bytes) {
        void* p = ws + off; off += (bytes + 255) & ~(size_t)255; return p;
    };
    unsigned short* x_bf  = (unsigned short*)alloc((size_t)M * D * 2);
    unsigned short* Wqk_t = (unsigned short*)alloc((size_t)512 * D * 2);
    unsigned short* Wv_t  = (unsigned short*)alloc((size_t)D * D * 2);
    unsigned short* QK_bf = (unsigned short*)alloc((size_t)M * 512 * 2);
    unsigned short* Vt_bf = (unsigned short*)alloc((size_t)D * M * 2);

    float* outO = (float*)d_out;                       // [4][2048][1024]
    float* outW = (float*)d_out + (size_t)M * D;       // [4][2048][2048]

    // 1. conversions
    convert_bf16<<<dim3((M * D / 4 + 255) / 256), 256, 0, stream>>>(x, x_bf, M * D / 4);
    tconvert<<<dim3(DA / 32, D / 32), dim3(32, 8), 0, stream>>>(Wq, Wqk_t, D, DA, 1.f / 16.f);
    tconvert<<<dim3(DA / 32, D / 32), dim3(32, 8), 0, stream>>>(Wk, Wqk_t + (size_t)256 * D, D, DA, 1.f);
    tconvert<<<dim3(D / 32, D / 32), dim3(32, 8), 0, stream>>>(Wv, Wv_t, D, D, 1.f);

    // 2. QK-concat GEMM: [8192 x 512] = x_bf @ Wqk_t^T
    gemm_bt_bf16<<<dim3(512 / BN, M / BM), 256, 0, stream>>>(x_bf, D, Wqk_t, D, QK_bf, 512, D);
    // 2b. V^T GEMM: [1024 x 8192] = Wv_t @ x_bf^T
    gemm_bt_bf16<<<dim3(M / BN, D / BM), 256, 0, stream>>>(Wv_t, D, x_bf, D, Vt_bf, M, D);

    // 3. scores -> E = exp(QK^T/16), causal masked, fp32 into weights region
    gemm_scores<<<dim3(T / BN, T / BM, B), 256, 0, stream>>>(QK_bf, outW);

    // 4. row-normalize in place (writes exact zeros above diagonal)
    softmax_norm<<<dim3(M), 256, 0, stream>>>(outW);

    // 5. PV GEMM with causal k-limit; reads normalized fp32 weights
    gemm_pv<<<dim3(D / BN, T / BM, B), 256, 0, stream>>>(outW, Vt_bf, outO);
}

// Round 2
// 158.625 us; speedup vs baseline: 1.1481x; 1.1481x over previous
//
#include <hip/hip_runtime.h>

// CausalSelfAttention: B=4, T=2048, D=1024, DA=256, fp32 in/out.
// Pipeline: convert->bf16, QKV GEMMs (MFMA), scores+exp GEMM (with zero-fill
// of masked tiles), causal row-normalize (also emits bf16 P), PV GEMM (bf16).

typedef short bf16x8 __attribute__((ext_vector_type(8)));   // 8 bf16 in 4 VGPRs
typedef float f32x4  __attribute__((ext_vector_type(4)));
typedef unsigned int  u32x4 __attribute__((ext_vector_type(4)));
typedef unsigned short u16x4 __attribute__((ext_vector_type(4)));

static __device__ __forceinline__ unsigned short f2bf(float f) {
    union { float f; unsigned int u; } v; v.f = f;
    unsigned int u = v.u;
    return (unsigned short)((u + 0x7FFFu + ((u >> 16) & 1u)) >> 16);  // RNE
}

// ---------------- conversion kernels ----------------

__global__ void convert_bf16(const float* __restrict__ in,
                             unsigned short* __restrict__ out, int n4) {
    int i = blockIdx.x * blockDim.x + threadIdx.x;
    if (i >= n4) return;
    f32x4 v = ((const f32x4*)in)[i];
    u16x4 o;
    o[0] = f2bf(v[0]); o[1] = f2bf(v[1]); o[2] = f2bf(v[2]); o[3] = f2bf(v[3]);
    ((u16x4*)out)[i] = o;
}

// W[K][N] (fp32) -> Wt[N][K] (bf16), scaled.
__global__ void tconvert(const float* __restrict__ W,
                         unsigned short* __restrict__ Wt,
                         int K, int N, float scale) {
    __shared__ float tile[32][33];
    int n0 = blockIdx.x * 32, k0 = blockIdx.y * 32;
    int tx = threadIdx.x, ty = threadIdx.y;
#pragma unroll
    for (int r = 0; r < 4; ++r)
        tile[ty + 8 * r][tx] = W[(size_t)(k0 + ty + 8 * r) * N + n0 + tx];
    __syncthreads();
#pragma unroll
    for (int r = 0; r < 4; ++r)
        Wt[(size_t)(n0 + ty + 8 * r) * K + k0 + tx] = f2bf(tile[tx][ty + 8 * r] * scale);
}

// ---------------- GEMM (A[M,K] @ Bt[N,K]^T), bf16 in, bf16 out ----------------

#define BM 128
#define BN 128
#define BK 64
#define BKP 72   // padded LDS leading dim (+16B) to break bank conflicts

__global__ __launch_bounds__(256) void gemm_bt_bf16(
    const unsigned short* __restrict__ A, int lda,
    const unsigned short* __restrict__ Bt, int ldb,
    unsigned short* __restrict__ C, int ldc, int K)
{
    __shared__ __align__(16) unsigned short As[BM][BKP];
    __shared__ __align__(16) unsigned short Bs[BN][BKP];
    int tid = threadIdx.x;
    int m0 = blockIdx.y * BM, n0 = blockIdx.x * BN;
    int lane = tid & 63, wave = tid >> 6;
    int wr = (wave >> 1) * 64, wc = (wave & 1) * 64;
    int fr = lane & 15, fk = (lane >> 4) * 8;
    int srow = tid >> 3, scol = (tid & 7) * 8;
    f32x4 acc[4][4] = {};

    for (int kt = 0; kt < K; kt += BK) {
        const unsigned short* Ap = A + (size_t)(m0 + srow) * lda + kt + scol;
        const unsigned short* Bp = Bt + (size_t)(n0 + srow) * ldb + kt + scol;
#pragma unroll
        for (int i = 0; i < 4; ++i) {
            *(u32x4*)(&As[srow + 32 * i][scol]) = *(const u32x4*)(Ap + (size_t)32 * i * lda);
            *(u32x4*)(&Bs[srow + 32 * i][scol]) = *(const u32x4*)(Bp + (size_t)32 * i * ldb);
        }
        __syncthreads();
#pragma unroll
        for (int ks = 0; ks < BK; ks += 32) {
            bf16x8 af[4], bfr[4];
#pragma unroll
            for (int i = 0; i < 4; ++i) af[i]  = *(const bf16x8*)(&As[wr + 16 * i + fr][ks + fk]);
#pragma unroll
            for (int j = 0; j < 4; ++j) bfr[j] = *(const bf16x8*)(&Bs[wc + 16 * j + fr][ks + fk]);
#pragma unroll
            for (int i = 0; i < 4; ++i)
#pragma unroll
                for (int j = 0; j < 4; ++j)
                    acc[i][j] = __builtin_amdgcn_mfma_f32_16x16x32_bf16(af[i], bfr[j], acc[i][j], 0, 0, 0);
        }
        __syncthreads();
    }
#pragma unroll
    for (int i = 0; i < 4; ++i)
#pragma unroll
        for (int j = 0; j < 4; ++j)
#pragma unroll
            for (int r = 0; r < 4; ++r) {
                int row = m0 + wr + 16 * i + (lane >> 4) * 4 + r;
                int col = n0 + wc + 16 * j + fr;
                C[(size_t)row * ldc + col] = f2bf(acc[i][j][r]);
            }
}

// ---------------- scores: E = exp(Q Kt^T), causal-masked, fp32 out ----------------
// QK buffer: [8192][512] bf16, Q = cols 0:256, K = cols 256:512. Per batch z.
// Fully-masked tiles (n0 > m0) get a store-only zero fill (d_out is poisoned).

__global__ __launch_bounds__(256) void gemm_scores(
    const unsigned short* __restrict__ QK, float* __restrict__ Wout)
{
    int b = blockIdx.z;
    int m0 = blockIdx.y * BM, n0 = blockIdx.x * BN;
    float* Wb = Wout + (size_t)b * 2048 * 2048;
    int tid = threadIdx.x;

    if (n0 > m0) {  // fully above diagonal: zero-fill only
        int row = m0 + (tid >> 1);
        float* p = Wb + (size_t)row * 2048 + n0 + (tid & 1) * 64;
        f32x4 z = {};
#pragma unroll
        for (int i = 0; i < 16; ++i) ((f32x4*)p)[i] = z;
        return;
    }

    const unsigned short* A  = QK + (size_t)b * 2048 * 512;
    const unsigned short* Bt = A + 256;

    __shared__ __align__(16) unsigned short As[BM][BKP];
    __shared__ __align__(16) unsigned short Bs[BN][BKP];
    int lane = tid & 63, wave = tid >> 6;
    int wr = (wave >> 1) * 64, wc = (wave & 1) * 64;
    int fr = lane & 15, fk = (lane >> 4) * 8;
    int srow = tid >> 3, scol = (tid & 7) * 8;
    f32x4 acc[4][4] = {};

    for (int kt = 0; kt < 256; kt += BK) {
        const unsigned short* Ap = A  + (size_t)(m0 + srow) * 512 + kt + scol;
        const unsigned short* Bp = Bt + (size_t)(n0 + srow) * 512 + kt + scol;
#pragma unroll
        for (int i = 0; i < 4; ++i) {
            *(u32x4*)(&As[srow + 32 * i][scol]) = *(const u32x4*)(Ap + (size_t)32 * i * 512);
            *(u32x4*)(&Bs[srow + 32 * i][scol]) = *(const u32x4*)(Bp + (size_t)32 * i * 512);
        }
        __syncthreads();
#pragma unroll
        for (int ks = 0; ks < BK; ks += 32) {
            bf16x8 af[4], bfr[4];
#pragma unroll
            for (int i = 0; i < 4; ++i) af[i]  = *(const bf16x8*)(&As[wr + 16 * i + fr][ks + fk]);
#pragma unroll
            for (int j = 0; j < 4; ++j) bfr[j] = *(const bf16x8*)(&Bs[wc + 16 * j + fr][ks + fk]);
#pragma unroll
            for (int i = 0; i < 4; ++i)
#pragma unroll
                for (int j = 0; j < 4; ++j)
                    acc[i][j] = __builtin_amdgcn_mfma_f32_16x16x32_bf16(af[i], bfr[j], acc[i][j], 0, 0, 0);
        }
        __syncthreads();
    }
#pragma unroll
    for (int i = 0; i < 4; ++i)
#pragma unroll
        for (int j = 0; j < 4; ++j)
#pragma unroll
            for (int r = 0; r < 4; ++r) {
                int q = m0 + wr + 16 * i + (lane >> 4) * 4 + r;
                int k = n0 + wc + 16 * j + fr;
                Wb[(size_t)q * 2048 + k] = (k <= q) ? expf(acc[i][j][r]) : 0.f;
            }
}

// ---------------- row normalize (causal range only) + bf16 P emit ----------------
// One block per row. Above-diagonal fp32 zeros already exist (scores kernel);
// zeros stay zeros under scaling so we only rewrite chunks with c0 <= q.
// P_bf gets zeros up to the row's 128-tile boundary (all gemm_pv ever reads).

__global__ __launch_bounds__(256) void softmax_norm(float* __restrict__ Wt,
                                                    unsigned short* __restrict__ Pbf) {
    int r = blockIdx.x;          // 0..8191 == b*2048+q
    int q = r & 2047;
    float* row = Wt + (size_t)r * 2048;
    unsigned short* prow = Pbf + (size_t)r * 2048;
    int tid = threadIdx.x;
    int c0 = tid * 8;
    int tile_end = ((q >> 7) + 1) << 7;   // 128-boundary past q

    f32x4 v0 = {}, v1 = {};
    float s = 0.f;
    bool live = (c0 <= q);
    if (live) {
        v0 = *((const f32x4*)row + 2 * tid);
        v1 = *((const f32x4*)row + 2 * tid + 1);
#pragma unroll
        for (int j = 0; j < 4; ++j) s += v0[j] + v1[j];   // above-diag entries are exact 0
    }
#pragma unroll
    for (int off = 32; off > 0; off >>= 1) s += __shfl_xor(s, off, 64);
    __shared__ float red[4];
    if ((tid & 63) == 0) red[tid >> 6] = s;
    __syncthreads();
    float inv = 1.0f / (red[0] + red[1] + red[2] + red[3]);

    if (live) {
        unsigned short t[8];
#pragma unroll
        for (int j = 0; j < 4; ++j) {
            v0[j] *= inv; v1[j] *= inv;
            t[j] = f2bf(v0[j]); t[4 + j] = f2bf(v1[j]);
        }
        *((f32x4*)row + 2 * tid) = v0;
        *((f32x4*)row + 2 * tid + 1) = v1;
        *(u32x4*)(prow + c0) = *(const u32x4*)t;
    } else if (c0 < tile_end) {
        u32x4 z = {};
        *(u32x4*)(prow + c0) = z;   // zero pad P_bf to tile boundary
    }
}

// ---------------- PV: O = P_bf @ V, causal k-limit, XCD-balanced swizzle ----------------

__global__ __launch_bounds__(256) void gemm_pv(
    const unsigned short* __restrict__ P, const unsigned short* __restrict__ Vt,
    float* __restrict__ O)
{
    // 1-D grid of 512; decode so the 8 col-tiles sharing a P panel land on one
    // XCD, with row-tiles y and 15-y paired per XCD (balanced causal work),
    // longest tiles dispatched first.
    int lin = blockIdx.x;
    int j   = lin & 7;        // target XCD
    int idx = lin >> 3;       // 0..63
    int x   = idx & 7;        // col tile
    int h   = idx >> 3;       // 0..7
    int b   = h >> 1;         // batch
    int y   = (h & 1) ? j : 15 - j;   // row tile

    int m0 = y * BM, n0 = x * BN;
    const unsigned short* Pb = P + (size_t)b * 2048 * 2048;
    const unsigned short* Bt = Vt + (size_t)b * 2048;   // ldb = 8192
    float* Ob = O + (size_t)b * 2048 * 1024;
    int Klim = (y + 1) * BM;

    __shared__ __align__(16) unsigned short As[BM][BKP];
    __shared__ __align__(16) unsigned short Bs[BN][BKP];
    int tid = threadIdx.x;
    int lane = tid & 63, wave = tid >> 6;
    int wr = (wave >> 1) * 64, wc = (wave & 1) * 64;
    int fr = lane & 15, fk = (lane >> 4) * 8;
    int srow = tid >> 3, scol = (tid & 7) * 8;
    f32x4 acc[4][4] = {};

    for (int kt = 0; kt < Klim; kt += BK) {
        const unsigned short* Ap = Pb + (size_t)(m0 + srow) * 2048 + kt + scol;
        const unsigned short* Bp = Bt + (size_t)(n0 + srow) * 8192 + kt + scol;
#pragma unroll
        for (int i = 0; i < 4; ++i) {
            *(u32x4*)(&As[srow + 32 * i][scol]) = *(const u32x4*)(Ap + (size_t)32 * i * 2048);
            *(u32x4*)(&Bs[srow + 32 * i][scol]) = *(const u32x4*)(Bp + (size_t)32 * i * 8192);
        }
        __syncthreads();
#pragma unroll
        for (int ks = 0; ks < BK; ks += 32) {
            bf16x8 af[4], bfr[4];
#pragma unroll
            for (int i = 0; i < 4; ++i) af[i]  = *(const bf16x8*)(&As[wr + 16 * i + fr][ks + fk]);
#pragma unroll
            for (int jj = 0; jj < 4; ++jj) bfr[jj] = *(const bf16x8*)(&Bs[wc + 16 * jj + fr][ks + fk]);
#pragma unroll
            for (int i = 0; i < 4; ++i)
#pragma unroll
                for (int jj = 0; jj < 4; ++jj)
                    acc[i][jj] = __builtin_amdgcn_mfma_f32_16x16x32_bf16(af[i], bfr[jj], acc[i][jj], 0, 0, 0);
        }
        __syncthreads();
    }
#pragma unroll
    for (int i = 0; i < 4; ++i)
#pragma unroll
        for (int jj = 0; jj < 4; ++jj)
#pragma unroll
            for (int r = 0; r < 4; ++r) {
                int row = m0 + wr + 16 * i + (lane >> 4) * 4 + r;
                int col = n0 + wc + 16 * jj + fr;
                Ob[(size_t)row * 1024 + col] = acc[i][jj][r];
            }
}

// ---------------- launcher ----------------

extern "C" void kernel_launch(void* const* d_in, const int* in_sizes, int n_in,
                              void* d_out, int out_size, void* d_ws, size_t ws_size,
                              hipStream_t stream) {
    (void)in_sizes; (void)n_in; (void)out_size; (void)ws_size;
    const float* x  = (const float*)d_in[0];
    const float* Wq = (const float*)d_in[1];
    const float* Wk = (const float*)d_in[2];
    const float* Wv = (const float*)d_in[3];
    const int B = 4, T = 2048, D = 1024, DA = 256;
    const int M = B * T;  // 8192

    char* ws = (char*)d_ws;
    size_t off = 0;
    auto alloc = [&](size_t bytes) {
        void* p = ws + off; off += (bytes + 255) & ~(size_t)255; return p;
    };
    unsigned short* x_bf  = (unsigned short*)alloc((size_t)M * D * 2);
    unsigned short* Wqk_t = (unsigned short*)alloc((size_t)512 * D * 2);
    unsigned short* Wv_t  = (unsigned short*)alloc((size_t)D * D * 2);
    unsigned short* QK_bf = (unsigned short*)alloc((size_t)M * 512 * 2);
    unsigned short* Vt_bf = (unsigned short*)alloc((size_t)D * M * 2);
    unsigned short* P_bf  = (unsigned short*)alloc((size_t)M * T * 2);

    float* outO = (float*)d_out;                       // [4][2048][1024]
    float* outW = (float*)d_out + (size_t)M * D;       // [4][2048][2048]

    // 1. conversions
    convert_bf16<<<dim3((M * D / 4 + 255) / 256), 256, 0, stream>>>(x, x_bf, M * D / 4);
    tconvert<<<dim3(DA / 32, D / 32), dim3(32, 8), 0, stream>>>(Wq, Wqk_t, D, DA, 1.f / 16.f);
    tconvert<<<dim3(DA / 32, D / 32), dim3(32, 8), 0, stream>>>(Wk, Wqk_t + (size_t)256 * D, D, DA, 1.f);
    tconvert<<<dim3(D / 32, D / 32), dim3(32, 8), 0, stream>>>(Wv, Wv_t, D, D, 1.f);

    // 2. QK-concat GEMM: [8192 x 512] = x_bf @ Wqk_t^T
    gemm_bt_bf16<<<dim3(512 / BN, M / BM), 256, 0, stream>>>(x_bf, D, Wqk_t, D, QK_bf, 512, D);
    // 2b. V^T GEMM: [1024 x 8192] = Wv_t @ x_bf^T
    gemm_bt_bf16<<<dim3(M / BN, D / BM), 256, 0, stream>>>(Wv_t, D, x_bf, D, Vt_bf, M, D);

    // 3. scores -> E = exp(QK^T/16), causal masked (+zero-fill of masked tiles)
    gemm_scores<<<dim3(T / BN, T / BM, B), 256, 0, stream>>>(QK_bf, outW);

    // 4. row-normalize causal range in place; emit bf16 P
    softmax_norm<<<dim3(M), 256, 0, stream>>>(outW, P_bf);

    // 5. PV GEMM (bf16 P) with causal k-limit, balanced XCD swizzle
    gemm_pv<<<dim3(512), 256, 0, stream>>>(P_bf, Vt_bf, outO);
}

// Round 3
// 151.221 us; speedup vs baseline: 1.2043x; 1.0490x over previous
//
#include <hip/hip_runtime.h>

// CausalSelfAttention: B=4, T=2048, D=1024, DA=256, fp32 in/out.
// Pipeline: convert->bf16, QKV GEMMs (global_load_lds MFMA), scores->bf16 E +
// partial row-sums, finalize (normalized fp32 W + inv), PV GEMM scaled by inv.

typedef short bf16x8 __attribute__((ext_vector_type(8)));   // 8 bf16 in 4 VGPRs
typedef float f32x4  __attribute__((ext_vector_type(4)));
typedef unsigned int  u32x4 __attribute__((ext_vector_type(4)));
typedef unsigned short u16x4 __attribute__((ext_vector_type(4)));

static __device__ __forceinline__ unsigned short f2bf(float f) {
    union { float f; unsigned int u; } v; v.f = f;
    unsigned int u = v.u;
    return (unsigned short)((u + 0x7FFFu + ((u >> 16) & 1u)) >> 16);  // RNE
}

// async global->LDS, 16B per lane; LDS dest must be wave-linear (lane*16).
#define GLL(g, l) __builtin_amdgcn_global_load_lds( \
    (const __attribute__((address_space(1))) void*)(g), \
    (__attribute__((address_space(3))) void*)(l), 16, 0, 0)

// ---------------- conversion kernels ----------------

__global__ void convert_bf16(const float* __restrict__ in,
                             unsigned short* __restrict__ out, int n4) {
    int i = blockIdx.x * blockDim.x + threadIdx.x;
    if (i >= n4) return;
    f32x4 v = ((const f32x4*)in)[i];
    u16x4 o;
    o[0] = f2bf(v[0]); o[1] = f2bf(v[1]); o[2] = f2bf(v[2]); o[3] = f2bf(v[3]);
    ((u16x4*)out)[i] = o;
}

// W[K][N] (fp32) -> Wt[N][K] (bf16), scaled.
__global__ void tconvert(const float* __restrict__ W,
                         unsigned short* __restrict__ Wt,
                         int K, int N, float scale) {
    __shared__ float tile[32][33];
    int n0 = blockIdx.x * 32, k0 = blockIdx.y * 32;
    int tx = threadIdx.x, ty = threadIdx.y;
#pragma unroll
    for (int r = 0; r < 4; ++r)
        tile[ty + 8 * r][tx] = W[(size_t)(k0 + ty + 8 * r) * N + n0 + tx];
    __syncthreads();
#pragma unroll
    for (int r = 0; r < 4; ++r)
        Wt[(size_t)(n0 + ty + 8 * r) * K + k0 + tx] = f2bf(tile[tx][ty + 8 * r] * scale);
}

// ---------------- GEMM (A[M,K] @ Bt[N,K]^T), bf16 in, bf16 out ----------------

#define BM 128
#define BN 128
#define BK 64

__global__ __launch_bounds__(256) void gemm_bt_bf16(
    const unsigned short* __restrict__ A, int lda,
    const unsigned short* __restrict__ Bt, int ldb,
    unsigned short* __restrict__ C, int ldc, int K)
{
    __shared__ __align__(16) unsigned short As[BM][BK];
    __shared__ __align__(16) unsigned short Bs[BN][BK];
    int tid = threadIdx.x;
    int m0 = blockIdx.y * BM, n0 = blockIdx.x * BN;
    int lane = tid & 63, wave = tid >> 6;
    int wr = (wave >> 1) * 64, wc = (wave & 1) * 64;
    int fr = lane & 15, fk = (lane >> 4) * 8;
    int srow = tid >> 3, scol = (tid & 7) * 8;
    f32x4 acc[4][4] = {};

    for (int kt = 0; kt < K; kt += BK) {
        const unsigned short* Ap = A + (size_t)(m0 + srow) * lda + kt + scol;
        const unsigned short* Bp = Bt + (size_t)(n0 + srow) * ldb + kt + scol;
#pragma unroll
        for (int i = 0; i < 4; ++i) {
            GLL(Ap + (size_t)32 * i * lda, &As[srow + 32 * i][scol]);
            GLL(Bp + (size_t)32 * i * ldb, &Bs[srow + 32 * i][scol]);
        }
        __syncthreads();
#pragma unroll
        for (int ks = 0; ks < BK; ks += 32) {
            bf16x8 af[4], bfr[4];
#pragma unroll
            for (int i = 0; i < 4; ++i) af[i]  = *(const bf16x8*)(&As[wr + 16 * i + fr][ks + fk]);
#pragma unroll
            for (int j = 0; j < 4; ++j) bfr[j] = *(const bf16x8*)(&Bs[wc + 16 * j + fr][ks + fk]);
#pragma unroll
            for (int i = 0; i < 4; ++i)
#pragma unroll
                for (int j = 0; j < 4; ++j)
                    acc[i][j] = __builtin_amdgcn_mfma_f32_16x16x32_bf16(af[i], bfr[j], acc[i][j], 0, 0, 0);
        }
        __syncthreads();
    }
#pragma unroll
    for (int i = 0; i < 4; ++i)
#pragma unroll
        for (int j = 0; j < 4; ++j)
#pragma unroll
            for (int r = 0; r < 4; ++r) {
                int row = m0 + wr + 16 * i + (lane >> 4) * 4 + r;
                int col = n0 + wc + 16 * j + fr;
                C[(size_t)row * ldc + col] = f2bf(acc[i][j][r]);
            }
}

// ---------------- scores: E = exp(Q Kt^T) bf16 + partial row sums ----------------
// QK buffer: [8192][512] bf16, Q = cols 0:256, K = cols 256:512.
// Live (causal) tiles only: 544 blocks, XCD-bijective swizzle (544 = 8*68).

__global__ __launch_bounds__(256) void scores_e(
    const unsigned short* __restrict__ QK, unsigned short* __restrict__ Ebf,
    float* __restrict__ partials)
{
    int lin = blockIdx.x;                     // 0..543
    int swz = (lin & 7) * 68 + (lin >> 3);
    int b = swz / 136, t = swz - b * 136;
    int y = (int)floorf((sqrtf(8.f * (float)t + 1.f) - 1.f) * 0.5f);
    if ((y + 1) * (y + 2) / 2 <= t) ++y;
    if (y * (y + 1) / 2 > t) --y;
    int x = t - y * (y + 1) / 2;
    int m0 = y * 128, n0 = x * 128;

    const unsigned short* A  = QK + (size_t)b * 2048 * 512;
    const unsigned short* Bt = A + 256;
    unsigned short* Eb = Ebf + (size_t)b * 2048 * 2048;

    __shared__ __align__(16) unsigned short As[128][64];
    __shared__ __align__(16) unsigned short Bs[128][64];
    __shared__ float rowsum2[2][128];
    int tid = threadIdx.x;
    int lane = tid & 63, wave = tid >> 6;
    int wr = (wave >> 1) * 64, wc = (wave & 1) * 64;
    int fr = lane & 15, fk = (lane >> 4) * 8;
    int srow = tid >> 3, scol = (tid & 7) * 8;
    f32x4 acc[4][4] = {};

    for (int kt = 0; kt < 256; kt += 64) {
        const unsigned short* Ap = A  + (size_t)(m0 + srow) * 512 + kt + scol;
        const unsigned short* Bp = Bt + (size_t)(n0 + srow) * 512 + kt + scol;
#pragma unroll
        for (int i = 0; i < 4; ++i) {
            GLL(Ap + (size_t)32 * i * 512, &As[srow + 32 * i][scol]);
            GLL(Bp + (size_t)32 * i * 512, &Bs[srow + 32 * i][scol]);
        }
        __syncthreads();
#pragma unroll
        for (int ks = 0; ks < 64; ks += 32) {
            bf16x8 af[4], bfr[4];
#pragma unroll
            for (int i = 0; i < 4; ++i) af[i]  = *(const bf16x8*)(&As[wr + 16 * i + fr][ks + fk]);
#pragma unroll
            for (int j = 0; j < 4; ++j) bfr[j] = *(const bf16x8*)(&Bs[wc + 16 * j + fr][ks + fk]);
#pragma unroll
            for (int i = 0; i < 4; ++i)
#pragma unroll
                for (int j = 0; j < 4; ++j)
                    acc[i][j] = __builtin_amdgcn_mfma_f32_16x16x32_bf16(af[i], bfr[j], acc[i][j], 0, 0, 0);
        }
        __syncthreads();
    }

    // exp + mask + bf16 store + per-row partial sums
#pragma unroll
    for (int i = 0; i < 4; ++i)
#pragma unroll
        for (int r = 0; r < 4; ++r) {
            int q = m0 + wr + 16 * i + (lane >> 4) * 4 + r;
            float s = 0.f;
#pragma unroll
            for (int j = 0; j < 4; ++j) {
                int k = n0 + wc + 16 * j + fr;
                float e = (k <= q) ? __expf(acc[i][j][r]) : 0.f;
                Eb[(size_t)q * 2048 + k] = f2bf(e);
                s += e;
            }
            s += __shfl_xor(s, 1, 64); s += __shfl_xor(s, 2, 64);
            s += __shfl_xor(s, 4, 64); s += __shfl_xor(s, 8, 64);
            if (fr == 0) rowsum2[wave & 1][wr + 16 * i + (lane >> 4) * 4 + r] = s;
        }
    __syncthreads();
    if (tid < 128)
        partials[((size_t)b * 2048 + m0 + tid) * 16 + x] =
            rowsum2[0][tid] + rowsum2[1][tid];
}

// ---------------- finalize: W = E*inv (fp32, zeros above diag), inv out ----------------

__global__ __launch_bounds__(256) void finalize_w(
    const unsigned short* __restrict__ Ebf, const float* __restrict__ partials,
    float* __restrict__ Wout, float* __restrict__ invout)
{
    int r = blockIdx.x, q = r & 2047, tid = threadIdx.x;
    __shared__ float invs;
    if (tid < 64) {
        int nt = q >> 7;
        float p = (tid <= nt) ? partials[(size_t)r * 16 + tid] : 0.f;
        p += __shfl_xor(p, 1, 64); p += __shfl_xor(p, 2, 64);
        p += __shfl_xor(p, 4, 64); p += __shfl_xor(p, 8, 64);
        if (tid == 0) { float iv = 1.f / p; invs = iv; invout[r] = iv; }
    }
    __syncthreads();
    float iv = invs;
    const unsigned short* er = Ebf + (size_t)r * 2048;
    float* wrow = Wout + (size_t)r * 2048;
    int c0 = tid * 8;
    f32x4 o0 = {}, o1 = {};
    if (c0 <= q) {   // masked entries within the chunk are exact bf16 zeros
        bf16x8 e = *(const bf16x8*)(er + c0);
#pragma unroll
        for (int j = 0; j < 4; ++j) {
            union { unsigned int u; float f; } a, b;
            a.u = ((unsigned int)(unsigned short)e[j]) << 16;
            b.u = ((unsigned int)(unsigned short)e[j + 4]) << 16;
            o0[j] = a.f * iv; o1[j] = b.f * iv;
        }
    }
    *((f32x4*)wrow + 2 * tid) = o0;
    *((f32x4*)wrow + 2 * tid + 1) = o1;
}

// ---------------- PV: O = (E @ V) * inv, causal k-limit, XCD-balanced ----------------

__global__ __launch_bounds__(256) void gemm_pv(
    const unsigned short* __restrict__ P, const unsigned short* __restrict__ Vt,
    const float* __restrict__ Inv, float* __restrict__ O)
{
    int lin = blockIdx.x;
    int j   = lin & 7;        // target XCD
    int idx = lin >> 3;       // 0..63
    int x   = idx & 7;        // col tile
    int h   = idx >> 3;       // 0..7
    int b   = h >> 1;         // batch
    int y   = (h & 1) ? j : 15 - j;   // row tile (balanced causal work)

    int m0 = y * BM, n0 = x * BN;
    const unsigned short* Pb = P + (size_t)b * 2048 * 2048;
    const unsigned short* Bt = Vt + (size_t)b * 2048;   // ldb = 8192
    float* Ob = O + (size_t)b * 2048 * 1024;
    int Klim = (y + 1) * BM;

    __shared__ __align__(16) unsigned short As[BM][BK];
    __shared__ __align__(16) unsigned short Bs[BN][BK];
    int tid = threadIdx.x;
    int lane = tid & 63, wave = tid >> 6;
    int wr = (wave >> 1) * 64, wc = (wave & 1) * 64;
    int fr = lane & 15, fk = (lane >> 4) * 8;
    int srow = tid >> 3, scol = (tid & 7) * 8;
    f32x4 acc[4][4] = {};

    for (int kt = 0; kt < Klim; kt += BK) {
        const unsigned short* Ap = Pb + (size_t)(m0 + srow) * 2048 + kt + scol;
        const unsigned short* Bp = Bt + (size_t)(n0 + srow) * 8192 + kt + scol;
#pragma unroll
        for (int i = 0; i < 4; ++i) {
            GLL(Ap + (size_t)32 * i * 2048, &As[srow + 32 * i][scol]);
            GLL(Bp + (size_t)32 * i * 8192, &Bs[srow + 32 * i][scol]);
        }
        __syncthreads();
#pragma unroll
        for (int ks = 0; ks < BK; ks += 32) {
            bf16x8 af[4], bfr[4];
#pragma unroll
            for (int i = 0; i < 4; ++i) af[i]  = *(const bf16x8*)(&As[wr + 16 * i + fr][ks + fk]);
#pragma unroll
            for (int jj = 0; jj < 4; ++jj) bfr[jj] = *(const bf16x8*)(&Bs[wc + 16 * jj + fr][ks + fk]);
#pragma unroll
            for (int i = 0; i < 4; ++i)
#pragma unroll
                for (int jj = 0; jj < 4; ++jj)
                    acc[i][jj] = __builtin_amdgcn_mfma_f32_16x16x32_bf16(af[i], bfr[jj], acc[i][jj], 0, 0, 0);
        }
        __syncthreads();
    }
#pragma unroll
    for (int i = 0; i < 4; ++i)
#pragma unroll
        for (int r = 0; r < 4; ++r) {
            int row = m0 + wr + 16 * i + (lane >> 4) * 4 + r;
            float iv = Inv[(size_t)b * 2048 + row];
#pragma unroll
            for (int jj = 0; jj < 4; ++jj) {
                int col = n0 + wc + 16 * jj + fr;
                Ob[(size_t)row * 1024 + col] = acc[i][jj][r] * iv;
            }
        }
}

// ---------------- launcher ----------------

extern "C" void kernel_launch(void* const* d_in, const int* in_sizes, int n_in,
                              void* d_out, int out_size, void* d_ws, size_t ws_size,
                              hipStream_t stream) {
    (void)in_sizes; (void)n_in; (void)out_size; (void)ws_size;
    const float* x  = (const float*)d_in[0];
    const float* Wq = (const float*)d_in[1];
    const float* Wk = (const float*)d_in[2];
    const float* Wv = (const float*)d_in[3];
    const int B = 4, T = 2048, D = 1024, DA = 256;
    const int M = B * T;  // 8192

    char* ws = (char*)d_ws;
    size_t off = 0;
    auto alloc = [&](size_t bytes) {
        void* p = ws + off; off += (bytes + 255) & ~(size_t)255; return p;
    };
    unsigned short* x_bf  = (unsigned short*)alloc((size_t)M * D * 2);
    unsigned short* Wqk_t = (unsigned short*)alloc((size_t)512 * D * 2);
    unsigned short* Wv_t  = (unsigned short*)alloc((size_t)D * D * 2);
    unsigned short* QK_bf = (unsigned short*)alloc((size_t)M * 512 * 2);
    unsigned short* Vt_bf = (unsigned short*)alloc((size_t)D * M * 2);
    unsigned short* E_bf  = (unsigned short*)alloc((size_t)M * T * 2);
    float*          parts = (float*)alloc((size_t)M * 16 * 4);
    float*          invs  = (float*)alloc((size_t)M * 4);

    float* outO = (float*)d_out;                       // [4][2048][1024]
    float* outW = (float*)d_out + (size_t)M * D;       // [4][2048][2048]

    // 1. conversions
    convert_bf16<<<dim3((M * D / 4 + 255) / 256), 256, 0, stream>>>(x, x_bf, M * D / 4);
    tconvert<<<dim3(DA / 32, D / 32), dim3(32, 8), 0, stream>>>(Wq, Wqk_t, D, DA, 1.f / 16.f);
    tconvert<<<dim3(DA / 32, D / 32), dim3(32, 8), 0, stream>>>(Wk, Wqk_t + (size_t)256 * D, D, DA, 1.f);
    tconvert<<<dim3(D / 32, D / 32), dim3(32, 8), 0, stream>>>(Wv, Wv_t, D, D, 1.f);

    // 2. QK-concat GEMM: [8192 x 512] = x_bf @ Wqk_t^T
    gemm_bt_bf16<<<dim3(512 / BN, M / BM), 256, 0, stream>>>(x_bf, D, Wqk_t, D, QK_bf, 512, D);
    // 2b. V^T GEMM: [1024 x 8192] = Wv_t @ x_bf^T
    gemm_bt_bf16<<<dim3(M / BN, D / BM), 256, 0, stream>>>(Wv_t, D, x_bf, D, Vt_bf, M, D);

    // 3. scores -> bf16 E (unnormalized) + partial row sums (live tiles only)
    scores_e<<<dim3(544), 256, 0, stream>>>(QK_bf, E_bf, parts);

    // 4. finalize: normalized fp32 W to d_out (incl. zeros) + 1/rowsum
    finalize_w<<<dim3(M), 256, 0, stream>>>(E_bf, parts, outW, invs);

    // 5. PV GEMM on unnormalized E, scale by inv in epilogue
    gemm_pv<<<dim3(512), 256, 0, stream>>>(E_bf, Vt_bf, invs, outO);
}